// Round 3
// baseline (100.183 us; speedup 1.0000x reference)
//
#include <hip/hip_runtime.h>

// SegmentTree prefix-sum sampling, 2^24 leaves, 65536 queries.
// Fanout-32 tree, 2 kernels:
//   K1 build_lo: leaves -> E (2^19 nodes, 2 MB) -> D (2^14, 64 KB) in ws.
//   K2 descend: per-block prologue folds D -> C(512)/B(16)/root in LDS,
//     then per query: step16(B,LDS) -> step32(C,LDS) -> step32(D,global,L2-hot)
//     -> step32(E) -> step32(leaf).  Only 3 dependent global loads.
// Every stored level and every reconstructed intermediate uses the exact
// pairwise association of the reference build (reshape(-1,2).sum), so the
// descent is bit-identical to the fp32 reference. No fast-math.

#define BATCH_N 65536

// ws offsets in floats (128B-aligned)
#define OFF_E 0          // 524288 floats
#define OFF_D 524288     // 16384 floats  -> end 540672 floats (~2.16 MB)

#define C_STRIDE 36      // 32 floats/node + 4 pad (16B-aligned, bank-spread)

__device__ __forceinline__ float sum32_exact_s(const float* __restrict__ x) {
    float n[16], m[8], p[4];
#pragma unroll
    for (int i = 0; i < 16; ++i) n[i] = x[2*i] + x[2*i+1];
#pragma unroll
    for (int i = 0; i < 8; ++i) m[i] = n[2*i] + n[2*i+1];
#pragma unroll
    for (int i = 0; i < 4; ++i) p[i] = m[2*i] + m[2*i+1];
    return (p[0] + p[1]) + (p[2] + p[3]);
}

// leaves -> E, D.  grid 2048 x 256; each thread folds 32 contiguous leaves (128B).
__global__ __launch_bounds__(256) void build_lo(const float* __restrict__ leaf,
                                                float* __restrict__ ws) {
    __shared__ float smE[256];
    const int t = threadIdx.x;
    const int b = blockIdx.x;
    const size_t gid = (size_t)b * 256 + t;        // E-node id, < 2^19
    const float4* q = reinterpret_cast<const float4*>(leaf) + gid * 8;
    float c[32];
#pragma unroll
    for (int k = 0; k < 8; ++k) {
        float4 v4 = q[k];
        c[4*k+0] = v4.x; c[4*k+1] = v4.y; c[4*k+2] = v4.z; c[4*k+3] = v4.w;
    }
    float e = sum32_exact_s(c);
    ws[OFF_E + gid] = e;
    smE[t] = e;
    __syncthreads();
    if (t < 8) {
        float d = sum32_exact_s(&smE[32 * t]);
        ws[OFF_D + (size_t)b * 8 + t] = d;
    }
}

// One fanout-32 step: read 32 children of node p (contiguous, STRIDE between
// nodes), resolve 5 bit-exact binary levels in-register.
template <int STRIDE>
__device__ __forceinline__ void step32(const float* __restrict__ base, int& p, float& v,
                                       float& picked) {
    const float* node = base + (size_t)p * STRIDE;
    float c[32];
#pragma unroll
    for (int k = 0; k < 8; ++k) {
        float4 v4 = reinterpret_cast<const float4*>(node)[k];
        c[4*k+0] = v4.x; c[4*k+1] = v4.y; c[4*k+2] = v4.z; c[4*k+3] = v4.w;
    }
    float n[16], m[8], P[4];
#pragma unroll
    for (int i = 0; i < 16; ++i) n[i] = c[2*i] + c[2*i+1];
#pragma unroll
    for (int i = 0; i < 8; ++i) m[i] = n[2*i] + n[2*i+1];
#pragma unroll
    for (int i = 0; i < 4; ++i) P[i] = m[2*i] + m[2*i+1];
    float q0 = P[0] + P[1];

    int ia = q0 < v;  if (ia) v -= q0;
    float pp = ia ? P[2] : P[0];
    int ib = pp < v;  if (ib) v -= pp;
    float mm = ia ? (ib ? m[6] : m[4]) : (ib ? m[2] : m[0]);
    int ic = mm < v;  if (ic) v -= mm;
    float na = ib ? (ic ? n[6]  : n[4])  : (ic ? n[2]  : n[0]);
    float nb = ib ? (ic ? n[14] : n[12]) : (ic ? n[10] : n[8]);
    float nn = ia ? nb : na;
    int id = nn < v;  if (id) v -= nn;
    // select even/odd child among 16 candidates each (bits ia,ib,ic,id)
    float e0 = id ? c[2]  : c[0],  e1 = id ? c[6]  : c[4];
    float e2 = id ? c[10] : c[8],  e3 = id ? c[14] : c[12];
    float e4 = id ? c[18] : c[16], e5 = id ? c[22] : c[20];
    float e6 = id ? c[26] : c[24], e7 = id ? c[30] : c[28];
    float f0 = ic ? e1 : e0, f1 = ic ? e3 : e2, f2 = ic ? e5 : e4, f3 = ic ? e7 : e6;
    float g0 = ib ? f1 : f0, g1 = ib ? f3 : f2;
    float ce = ia ? g1 : g0;
    float o0 = id ? c[3]  : c[1],  o1 = id ? c[7]  : c[5];
    float o2 = id ? c[11] : c[9],  o3 = id ? c[15] : c[13];
    float o4 = id ? c[19] : c[17], o5 = id ? c[23] : c[21];
    float o6 = id ? c[27] : c[25], o7 = id ? c[31] : c[29];
    float h0 = ic ? o1 : o0, h1 = ic ? o3 : o2, h2 = ic ? o5 : o4, h3 = ic ? o7 : o6;
    float k0 = ib ? h1 : h0, k1 = ib ? h3 : h2;
    float co = ia ? k1 : k0;
    int ie = ce < v;  if (ie) v -= ce;
    picked = ie ? co : ce;
    p = p * 32 + ia * 16 + ib * 8 + ic * 4 + id * 2 + ie;
}

// descend with fused top-build.  grid 256 x 256.
__global__ __launch_bounds__(256) void descend(const float* __restrict__ leaf,
                                               const float* __restrict__ frac,
                                               const float* __restrict__ ws,
                                               float* __restrict__ out) {
    __shared__ float smC[16 * C_STRIDE];   // 16 groups x 32 nodes, padded
    __shared__ float smB[16];
    __shared__ float smRoot;
    const int t = threadIdx.x;
    const float* D = ws + OFF_D;

    // prologue: D(16384) -> C(512) in LDS, padded layout
#pragma unroll
    for (int r = 0; r < 2; ++r) {
        int j = t + r * 256;               // C-node id, < 512
        const float4* q = reinterpret_cast<const float4*>(D) + (size_t)j * 8;
        float c[32];
#pragma unroll
        for (int k = 0; k < 8; ++k) {
            float4 v4 = q[k];
            c[4*k+0] = v4.x; c[4*k+1] = v4.y; c[4*k+2] = v4.z; c[4*k+3] = v4.w;
        }
        smC[(j >> 5) * C_STRIDE + (j & 31)] = sum32_exact_s(c);
    }
    __syncthreads();
    if (t < 16) {
        smB[t] = sum32_exact_s(&smC[t * C_STRIDE]);
    }
    __syncthreads();
    if (t == 0) {
        float x[16];
#pragma unroll
        for (int i = 0; i < 16; ++i) x[i] = smB[i];
        float n0 = x[0]+x[1], n1 = x[2]+x[3], n2 = x[4]+x[5], n3 = x[6]+x[7];
        float n4 = x[8]+x[9], n5 = x[10]+x[11], n6 = x[12]+x[13], n7 = x[14]+x[15];
        smRoot = ((n0+n1)+(n2+n3)) + ((n4+n5)+(n6+n7));
    }
    __syncthreads();

    const int tid = blockIdx.x * 256 + t;
    float v = frac[tid] * smRoot;
    float picked = 0.0f;

    // step16 over B (all lanes p=0: LDS broadcast, free)
    float x0 = smB[0],  x1 = smB[1],  x2 = smB[2],  x3 = smB[3];
    float x4 = smB[4],  x5 = smB[5],  x6 = smB[6],  x7 = smB[7];
    float x8 = smB[8],  x9 = smB[9],  xa = smB[10], xb = smB[11];
    float xc = smB[12], xd = smB[13], xe = smB[14], xf = smB[15];
    float n0 = x0+x1, n2 = x4+x5, n4 = x8+x9, n6 = xc+xd;
    float m0 = n0 + (x2+x3);
    float m2 = n4 + (xa+xb);
    float t0 = m0 + (n2 + (x6+x7));
    int ia = t0 < v;  if (ia) v -= t0;
    float mm = ia ? m2 : m0;
    int ib = mm < v;  if (ib) v -= mm;
    float nn = ia ? (ib ? n6 : n4) : (ib ? n2 : n0);
    int ic = nn < v;  if (ic) v -= nn;
    float se = ia ? (ib ? (ic ? xe : xc) : (ic ? xa : x8))
                  : (ib ? (ic ? x6 : x4) : (ic ? x2 : x0));
    int id = se < v;  if (id) v -= se;
    int p = ia * 8 + ib * 4 + ic * 2 + id;   // in [0,16)

    step32<C_STRIDE>(smC,        p, v, picked);   // LDS
    step32<32>(ws + OFF_D,       p, v, picked);   // 64 KB, L2-hot
    step32<32>(ws + OFF_E,       p, v, picked);   // 2 MB
    step32<32>(leaf,             p, v, picked);   // final picked == leaf[index]

    out[tid] = (float)p;                 // p < 2^24, exact in fp32
    out[BATCH_N + tid] = picked;
}

extern "C" void kernel_launch(void* const* d_in, const int* in_sizes, int n_in,
                              void* d_out, int out_size, void* d_ws, size_t ws_size,
                              hipStream_t stream) {
    const float* leaf = (const float*)d_in[0];
    const float* frac = (const float*)d_in[1];
    float* out = (float*)d_out;
    float* ws  = (float*)d_ws;

    hipLaunchKernelGGL(build_lo, dim3(2048), dim3(256), 0, stream, leaf, ws);
    hipLaunchKernelGGL(descend,  dim3(256),  dim3(256), 0, stream, leaf, frac, ws, out);
}

// Round 5
// 97.989 us; speedup vs baseline: 1.0224x; 1.0224x over previous
//
#include <hip/hip_runtime.h>

// SegmentTree prefix-sum sampling, 2^24 leaves, 65536 queries.
// Fanout-16 tree: store levels with 16, 256, 4096, 65536, 1048576 nodes + root
// (~4.5 MB ws). Every stored value and every reconstructed intermediate uses
// the exact pairwise association of the reference build
// (((a+b)+(c+d))+((e+f)+(g+h)))... so the binary descent is bit-identical to
// the fp32 jax reference. No fast-math.
//
// Descent: 6 dependent 64B loads per query (4 binary levels resolved per step,
// final step's line IS the leaf gather).
//
// NOTE (R1-R4 evidence): total dur_us ~98-100 is dominated by harness reset
// (256 MB d_ws poison + 64 MB input restore ~ 85 us at write-BW floor, visible
// as fillBufferAligned dispatches at 6.3-6.5 TB/s in every profile). Kernel-
// controllable share ~15 us: build_lo at ~80% HBM peak reading the mandatory
// 64 MB of leaves, descend latency-bound at ~3-6 us. Structure-insensitive
// across 4-kernel/8-step, 3-kernel/6-step, 2-kernel/3-step variants; a fused
// cooperative single-kernel variant failed to launch (co-residency rejection).

#define BATCH_N 65536

// ws offsets in floats (all 64B-aligned)
#define OFF_ROOT 0
#define OFF_A 16       // 16 nodes   (children of root)
#define OFF_B 32       // 256
#define OFF_C 288      // 4096
#define OFF_D 4384     // 65536
#define OFF_E 69920    // 1048576   -> end 1118496 floats (~4.47 MB)

__device__ __forceinline__ float sum16_exact(float4 A, float4 B, float4 C, float4 D) {
    // 4 pairwise levels, matching the reference's reshape(-1,2).sum build
    float n0 = A.x + A.y, n1 = A.z + A.w, n2 = B.x + B.y, n3 = B.z + B.w;
    float n4 = C.x + C.y, n5 = C.z + C.w, n6 = D.x + D.y, n7 = D.z + D.w;
    float m0 = n0 + n1, m1 = n2 + n3, m2 = n4 + n5, m3 = n6 + n7;
    return (m0 + m1) + (m2 + m3);
}

__device__ __forceinline__ float sum16_exact_s(const float* __restrict__ x) {
    float n0 = x[0] + x[1],  n1 = x[2] + x[3],  n2 = x[4] + x[5],  n3 = x[6] + x[7];
    float n4 = x[8] + x[9],  n5 = x[10] + x[11], n6 = x[12] + x[13], n7 = x[14] + x[15];
    float m0 = n0 + n1, m1 = n2 + n3, m2 = n4 + n5, m3 = n6 + n7;
    return (m0 + m1) + (m2 + m3);
}

// leaves -> E (2^20), D (2^16), C (2^12).  grid 4096 x 256; thread folds 16 leaves.
__global__ __launch_bounds__(256) void build_lo(const float* __restrict__ leaf,
                                                float* __restrict__ ws) {
    __shared__ float smE[256];
    __shared__ float smD[16];
    const int t = threadIdx.x;
    const int b = blockIdx.x;
    const size_t gid = (size_t)b * 256 + t;
    const float4* q = reinterpret_cast<const float4*>(leaf) + gid * 4;
    float4 A = q[0], Bv = q[1], Cv = q[2], Dv = q[3];
    float e = sum16_exact(A, Bv, Cv, Dv);
    ws[OFF_E + gid] = e;
    smE[t] = e;
    __syncthreads();
    if (t < 16) {
        float d = sum16_exact_s(&smE[16 * t]);
        ws[OFF_D + (size_t)b * 16 + t] = d;
        smD[t] = d;
    }
    __syncthreads();
    if (t == 0) {
        ws[OFF_C + b] = sum16_exact_s(smD);
    }
}

// C (4096) -> B (256) -> A (16) -> root.  1 block x 256.
__global__ __launch_bounds__(256) void build_top(float* __restrict__ ws) {
    __shared__ float smB[256];
    __shared__ float smA[16];
    const int t = threadIdx.x;
    const float4* q = reinterpret_cast<const float4*>(ws + OFF_C) + (size_t)t * 4;
    float4 A = q[0], Bv = q[1], Cv = q[2], Dv = q[3];
    float bnode = sum16_exact(A, Bv, Cv, Dv);
    ws[OFF_B + t] = bnode;
    smB[t] = bnode;
    __syncthreads();
    if (t < 16) {
        float anode = sum16_exact_s(&smB[16 * t]);
        ws[OFF_A + t] = anode;
        smA[t] = anode;
    }
    __syncthreads();
    if (t == 0) {
        ws[OFF_ROOT] = sum16_exact_s(smA);
    }
}

// One fanout-16 step: read 16 children of node p (one 64B line), resolve 4
// bit-exact binary descent levels in-register. picked = chosen child value.
__device__ __forceinline__ void step16(const float* __restrict__ base, int& p, float& v,
                                       float& picked) {
    const float4* q = reinterpret_cast<const float4*>(base + (size_t)p * 16);
    float4 A = q[0], B = q[1], C = q[2], D = q[3];
    // reconstruct intermediate binary levels with the build's exact association
    float n0 = A.x + A.y, n2 = B.x + B.y, n4 = C.x + C.y, n6 = D.x + D.y;
    float m0 = n0 + (A.z + A.w);   // (c0+c1)+(c2+c3)
    float m2 = n4 + (C.z + C.w);   // (c8+c9)+(c10+c11)
    float t0 = m0 + (n2 + (B.z + B.w));  // left child at top binary level

    int ia = t0 < v;  if (ia) v -= t0;
    float mm = ia ? m2 : m0;
    int ib = mm < v;  if (ib) v -= mm;
    float nn = ia ? (ib ? n6 : n4) : (ib ? n2 : n0);
    int ic = nn < v;  if (ic) v -= nn;
    // even child c_{8ia+4ib+2ic} and odd child c_{...+1}
    float se0 = ia ? C.x : A.x, se1 = ia ? C.z : A.z;
    float se2 = ia ? D.x : B.x, se3 = ia ? D.z : B.z;
    float so0 = ia ? C.y : A.y, so1 = ia ? C.w : A.w;
    float so2 = ia ? D.y : B.y, so3 = ia ? D.w : B.w;
    float ce = ic ? (ib ? se3 : se1) : (ib ? se2 : se0);
    float co = ic ? (ib ? so3 : so1) : (ib ? so2 : so0);
    int id = ce < v;  if (id) v -= ce;
    picked = id ? co : ce;
    p = p * 16 + ia * 8 + ib * 4 + ic * 2 + id;
}

// 6-step descent per query.  grid 256 x 256.
__global__ __launch_bounds__(256) void descend(const float* __restrict__ leaf,
                                               const float* __restrict__ frac,
                                               const float* __restrict__ ws,
                                               float* __restrict__ out) {
    const int tid = blockIdx.x * 256 + threadIdx.x;
    float v = frac[tid] * ws[OFF_ROOT];
    int p = 0;
    float picked = 0.0f;
    step16(ws + OFF_A, p, v, picked);
    step16(ws + OFF_B, p, v, picked);
    step16(ws + OFF_C, p, v, picked);
    step16(ws + OFF_D, p, v, picked);
    step16(ws + OFF_E, p, v, picked);
    step16(leaf,       p, v, picked);   // final picked == leaf[index]
    out[tid] = (float)p;                // exact: p < 2^24
    out[BATCH_N + tid] = picked;
}

extern "C" void kernel_launch(void* const* d_in, const int* in_sizes, int n_in,
                              void* d_out, int out_size, void* d_ws, size_t ws_size,
                              hipStream_t stream) {
    const float* leaf = (const float*)d_in[0];
    const float* frac = (const float*)d_in[1];
    float* out = (float*)d_out;
    float* ws  = (float*)d_ws;

    hipLaunchKernelGGL(build_lo,  dim3(4096), dim3(256), 0, stream, leaf, ws);
    hipLaunchKernelGGL(build_top, dim3(1),    dim3(256), 0, stream, ws);
    hipLaunchKernelGGL(descend,   dim3(256),  dim3(256), 0, stream, leaf, frac, ws, out);
}